// Round 2
// baseline (612.445 us; speedup 1.0000x reference)
//
#include <hip/hip_runtime.h>
#include <hip/hip_bf16.h>

// EdgeProbMLP: out[e] = sigmoid( relu( [x*y, x-y] @ W1.T + b1 ) @ W2.T + b2 )
// where x = relu(nf[src] @ Wdim.T + bdim), y = same for dst.
// Strategy: precompute P[n] = relu(proj(nf[n])) once (bf16, in d_ws),
// then per-edge MFMA GEMM with W1 resident in LDS (bf16, XOR-swizzled).
// R2: upfront full-row gather staging + 2-deep software pipeline (prefetch
// next tile's ei + rows during current tile's compute) to fix latency bound.

#define N_NODES 100000
#define N_EDGES 1000000
#define N_TILES 31250

typedef unsigned int u32;
typedef u32   u32x2 __attribute__((ext_vector_type(2)));
typedef u32   u32x4 __attribute__((ext_vector_type(4)));
typedef float f32x4 __attribute__((ext_vector_type(4)));
typedef float f32x16 __attribute__((ext_vector_type(16)));
typedef __bf16 bf16x8 __attribute__((ext_vector_type(8)));

__device__ inline u32 pack2bf(float a, float b) {
    unsigned short ua = __builtin_bit_cast(unsigned short, (__bf16)a);
    unsigned short ub = __builtin_bit_cast(unsigned short, (__bf16)b);
    return (u32)ua | ((u32)ub << 16);
}
__device__ inline float bflo(u32 u) { return __builtin_bit_cast(float, u << 16); }
__device__ inline float bfhi(u32 u) { return __builtin_bit_cast(float, u & 0xFFFF0000u); }

// ---------------------------------------------------------------------------
// Kernel 1: P[n][c] = relu(sum_k nf[n][k] * Wdim[c][k] + bdim[c]), bf16 out.
// ---------------------------------------------------------------------------
__global__ __launch_bounds__(256, 2) void k_project(
    const float* __restrict__ nf, const float* __restrict__ Wdim,
    const float* __restrict__ bdim, unsigned short* __restrict__ P)
{
    __shared__ unsigned char lA[128 * 256];  // 32 KB: Wdim as bf16 [128ch][128k]
    const int t = threadIdx.x;
    for (int ci = t; ci < 2048; ci += 256) {          // 2048 chunks of 8 elems
        const int row = ci >> 4;                      // 16 chunks per 128-elem row
        const int k8 = (ci & 15) << 3;
        const float* wp = Wdim + (row << 7) + k8;
        f32x4 v0 = *(const f32x4*)wp;
        f32x4 v1 = *(const f32x4*)(wp + 4);
        u32x4 pk = { pack2bf(v0[0], v0[1]), pack2bf(v0[2], v0[3]),
                     pack2bf(v1[0], v1[1]), pack2bf(v1[2], v1[3]) };
        int byte = (row << 8) + (k8 << 1);
        byte ^= (row & 15) << 4;
        *(u32x4*)(lA + byte) = pk;
    }
    __syncthreads();

    const int lane = t & 63;
    const int wave = t >> 6;
    const int cc = lane & 31;     // node column
    const int h  = lane >> 5;     // k-half within MFMA
    const int tile = blockIdx.x * 4 + wave;
    if (tile >= 3125) return;
    const int node = (tile << 5) + cc;
    const float* xrow = nf + ((size_t)node << 7);

    // stage this lane's half of the row upfront (16 x 16B loads in flight)
    f32x4 rv[16];
#pragma unroll
    for (int kt = 0; kt < 8; ++kt) {
        const int kf = (kt << 4) + (h << 3);
        rv[2*kt]   = *(const f32x4*)(xrow + kf);
        rv[2*kt+1] = *(const f32x4*)(xrow + kf + 4);
    }

    f32x16 acc[4] = {};
#pragma unroll
    for (int kt = 0; kt < 8; ++kt) {                  // K = 128 = 8 * 16
        const int kf = (kt << 4) + (h << 3);
        f32x4 v0 = rv[2*kt], v1 = rv[2*kt+1];
        bf16x8 bf;
        bf[0]=(__bf16)v0[0]; bf[1]=(__bf16)v0[1]; bf[2]=(__bf16)v0[2]; bf[3]=(__bf16)v0[3];
        bf[4]=(__bf16)v1[0]; bf[5]=(__bf16)v1[1]; bf[6]=(__bf16)v1[2]; bf[7]=(__bf16)v1[3];
        const int off = kf << 1;                      // byte offset within LDS row
#pragma unroll
        for (int t4 = 0; t4 < 4; ++t4) {
            const int arow = (t4 << 5) + cc;
            const int ab = ((arow << 8) + off) ^ ((arow & 15) << 4);
            bf16x8 af = __builtin_bit_cast(bf16x8, *(const u32x4*)(lA + ab));
            acc[t4] = __builtin_amdgcn_mfma_f32_32x32x16_bf16(af, bf, acc[t4], 0, 0, 0);
        }
    }
    unsigned short* prow = P + ((size_t)node << 7);
#pragma unroll
    for (int t4 = 0; t4 < 4; ++t4) {
#pragma unroll
        for (int q = 0; q < 4; ++q) {
            const int chb = (t4 << 5) + (q << 3) + (h << 2);
            f32x4 bb = *(const f32x4*)(bdim + chb);
            const float h0 = fmaxf(acc[t4][(q << 2) + 0] + bb[0], 0.f);
            const float h1 = fmaxf(acc[t4][(q << 2) + 1] + bb[1], 0.f);
            const float h2 = fmaxf(acc[t4][(q << 2) + 2] + bb[2], 0.f);
            const float h3 = fmaxf(acc[t4][(q << 2) + 3] + bb[3], 0.f);
            u32x2 st = { pack2bf(h0, h1), pack2bf(h2, h3) };
            *(u32x2*)(prow + chb) = st;
        }
    }
}

// ---------------------------------------------------------------------------
// Kernel 2: per-edge MLP, 32 edges per wave-tile, pipelined gathers.
// ---------------------------------------------------------------------------
struct Rows { u32x4 v[16]; };   // [0..7]=src row chunks, [8..15]=dst row chunks

__device__ inline void issue_rows(const unsigned short* __restrict__ P,
                                  int si, int di, int h, Rows& r) {
    const unsigned char* ps = (const unsigned char*)(P + ((size_t)si << 7));
    const unsigned char* pd = (const unsigned char*)(P + ((size_t)di << 7));
#pragma unroll
    for (int kt = 0; kt < 8; ++kt) {
        const int off = (kt << 5) + (h << 4);
        r.v[kt]     = *(const u32x4*)(ps + off);
        r.v[8 + kt] = *(const u32x4*)(pd + off);
    }
}

__device__ inline void compute_store(const Rows& r, const unsigned char* lA,
                                     const float* __restrict__ b1,
                                     const float* __restrict__ W2, float b2v,
                                     float* __restrict__ out,
                                     int tile, int cc, int h) {
    f32x16 acc[4] = {};
#pragma unroll
    for (int kt = 0; kt < 8; ++kt) {
        const int off = (kt << 5) + (h << 4);
        u32x4 ux = r.v[kt];
        u32x4 uy = r.v[8 + kt];
        float fx[8], fy[8];
#pragma unroll
        for (int j = 0; j < 4; ++j) {
            fx[2*j] = bflo(ux[j]); fx[2*j+1] = bfhi(ux[j]);
            fy[2*j] = bflo(uy[j]); fy[2*j+1] = bfhi(uy[j]);
        }
        bf16x8 bp, bd;
#pragma unroll
        for (int j = 0; j < 8; ++j) {
            bp[j] = (__bf16)(fx[j] * fy[j]);
            bd[j] = (__bf16)(fx[j] - fy[j]);
        }
#pragma unroll
        for (int t4 = 0; t4 < 4; ++t4) {          // product half: W1[:, 0:128]
            const int arow = (t4 << 5) + cc;
            const int ab = ((arow << 9) + off) ^ ((arow & 31) << 4);
            bf16x8 af = __builtin_bit_cast(bf16x8, *(const u32x4*)(lA + ab));
            acc[t4] = __builtin_amdgcn_mfma_f32_32x32x16_bf16(af, bp, acc[t4], 0, 0, 0);
        }
#pragma unroll
        for (int t4 = 0; t4 < 4; ++t4) {          // diff half: W1[:, 128:256]
            const int arow = (t4 << 5) + cc;
            const int ab = ((arow << 9) + 256 + off) ^ ((arow & 31) << 4);
            bf16x8 af = __builtin_bit_cast(bf16x8, *(const u32x4*)(lA + ab));
            acc[t4] = __builtin_amdgcn_mfma_f32_32x32x16_bf16(af, bd, acc[t4], 0, 0, 0);
        }
    }
    float partial = 0.f;
#pragma unroll
    for (int t4 = 0; t4 < 4; ++t4) {
#pragma unroll
        for (int q = 0; q < 4; ++q) {
            const int chb = (t4 << 5) + (q << 3) + (h << 2);
            f32x4 bb = *(const f32x4*)(b1 + chb);
            f32x4 ww = *(const f32x4*)(W2 + chb);
#pragma unroll
            for (int rr = 0; rr < 4; ++rr) {
                const float hv = fmaxf(acc[t4][(q << 2) + rr] + bb[rr], 0.f);
                partial += hv * ww[rr];
            }
        }
    }
    partial += __shfl_xor(partial, 32);           // sum the two k-half groups
    const float z = partial + b2v;
    const float prob = 1.0f / (1.0f + __expf(-z));
    if (h == 0) out[(tile << 5) + cc] = prob;
}

__global__ __launch_bounds__(256, 2) void k_edge(
    const unsigned short* __restrict__ P,
    const int* __restrict__ ei,          // [2][E] int32
    const float* __restrict__ W1, const float* __restrict__ b1,
    const float* __restrict__ W2, const float* __restrict__ b2,
    float* __restrict__ out)
{
    __shared__ unsigned char lA[128 * 512];  // 64 KB: W1 bf16 [128ch][256k]
    const int t = threadIdx.x;
    for (int ci = t; ci < 4096; ci += 256) {          // 4096 chunks of 8
        const int row = ci >> 5;                      // 32 chunks per 256-elem row
        const int k8 = (ci & 31) << 3;
        const float* wp = W1 + (row << 8) + k8;
        f32x4 v0 = *(const f32x4*)wp;
        f32x4 v1 = *(const f32x4*)(wp + 4);
        u32x4 pk = { pack2bf(v0[0], v0[1]), pack2bf(v0[2], v0[3]),
                     pack2bf(v1[0], v1[1]), pack2bf(v1[2], v1[3]) };
        int byte = (row << 9) + (k8 << 1);
        byte ^= (row & 31) << 4;
        *(u32x4*)(lA + byte) = pk;
    }
    __syncthreads();

    const int lane = t & 63;
    const int wave = t >> 6;
    const int cc = lane & 31;     // edge column within tile
    const int h  = lane >> 5;     // k-half
    const float b2v = b2[0];
    const int stride = gridDim.x << 2;

    const int t0 = blockIdx.x * 4 + wave;             // t0 < 2048 <= N_TILES
    int sn, dn;
    Rows A, B;
    {   // tile t0: ei + rows
        const int e0 = t0 << 5;
        const int sc = ei[e0 + cc];
        const int dc = ei[N_EDGES + e0 + cc];
        issue_rows(P, sc, dc, h, A);
    }
    {   // ei for t0+stride
        int tt = t0 + stride; tt = tt < N_TILES ? tt : N_TILES - 1;
        const int e0 = tt << 5;
        sn = ei[e0 + cc];
        dn = ei[N_EDGES + e0 + cc];
    }
    int tl = t0;

#define STEP(CUR, NXT)                                                        \
    {                                                                         \
        issue_rows(P, sn, dn, h, NXT);   /* prefetch rows for tl+stride */    \
        int tt = tl + 2 * stride; tt = tt < N_TILES ? tt : N_TILES - 1;       \
        const int e0n = tt << 5;                                              \
        sn = ei[e0n + cc];                                                    \
        dn = ei[N_EDGES + e0n + cc];                                          \
        compute_store(CUR, lA, b1, W2, b2v, out, tl, cc, h);                  \
        tl += stride;                                                         \
    }

    for (;;) {
        STEP(A, B);
        if (tl >= N_TILES) break;
        STEP(B, A);
        if (tl >= N_TILES) break;
    }
#undef STEP
}

extern "C" void kernel_launch(void* const* d_in, const int* in_sizes, int n_in,
                              void* d_out, int out_size, void* d_ws, size_t ws_size,
                              hipStream_t stream) {
    const float* nf   = (const float*)d_in[0];
    const int*   ei   = (const int*)d_in[1];
    const float* Wdim = (const float*)d_in[2];
    const float* bdim = (const float*)d_in[3];
    const float* W1   = (const float*)d_in[4];
    const float* b1   = (const float*)d_in[5];
    const float* W2   = (const float*)d_in[6];
    const float* b2   = (const float*)d_in[7];
    float* out = (float*)d_out;
    unsigned short* P = (unsigned short*)d_ws;        // 100000*128 bf16 = 25.6 MB

    k_project<<<dim3(782), dim3(256), 0, stream>>>(nf, Wdim, bdim, P);
    k_edge<<<dim3(512), dim3(256), 0, stream>>>(P, ei, W1, b1, W2, b2, out);
}

// Round 3
// 335.016 us; speedup vs baseline: 1.8281x; 1.8281x over previous
//
#include <hip/hip_runtime.h>
#include <hip/hip_bf16.h>

// EdgeProbMLP: out[e] = sigmoid( relu( [x*y, x-y] @ W1.T + b1 ) @ W2.T + b2 )
// where x = relu(nf[src] @ Wdim.T + bdim), y = same for dst.
// Strategy: precompute P[n] = relu(proj(nf[n])) once (bf16, in d_ws),
// then per-edge MFMA GEMM with W1 resident in LDS (bf16, XOR-swizzled).
// R3: fix R2's spill — launch_bounds(256,1) so the 2-deep pipeline's ~230
// VGPRs fit (occupancy is LDS-bound at 2 blocks/CU either way), and
// nontemporal P-row gathers to avoid L2 thrash (1.45 GB -> ~0.5 GB fetch).

#define N_NODES 100000
#define N_EDGES 1000000
#define N_TILES 31250

typedef unsigned int u32;
typedef u32   u32x2 __attribute__((ext_vector_type(2)));
typedef u32   u32x4 __attribute__((ext_vector_type(4)));
typedef float f32x4 __attribute__((ext_vector_type(4)));
typedef float f32x16 __attribute__((ext_vector_type(16)));
typedef __bf16 bf16x8 __attribute__((ext_vector_type(8)));

__device__ inline u32 pack2bf(float a, float b) {
    unsigned short ua = __builtin_bit_cast(unsigned short, (__bf16)a);
    unsigned short ub = __builtin_bit_cast(unsigned short, (__bf16)b);
    return (u32)ua | ((u32)ub << 16);
}
__device__ inline float bflo(u32 u) { return __builtin_bit_cast(float, u << 16); }
__device__ inline float bfhi(u32 u) { return __builtin_bit_cast(float, u & 0xFFFF0000u); }

// ---------------------------------------------------------------------------
// Kernel 1: P[n][c] = relu(sum_k nf[n][k] * Wdim[c][k] + bdim[c]), bf16 out.
// ---------------------------------------------------------------------------
__global__ __launch_bounds__(256, 1) void k_project(
    const float* __restrict__ nf, const float* __restrict__ Wdim,
    const float* __restrict__ bdim, unsigned short* __restrict__ P)
{
    __shared__ unsigned char lA[128 * 256];  // 32 KB: Wdim as bf16 [128ch][128k]
    const int t = threadIdx.x;
    for (int ci = t; ci < 2048; ci += 256) {          // 2048 chunks of 8 elems
        const int row = ci >> 4;                      // 16 chunks per 128-elem row
        const int k8 = (ci & 15) << 3;
        const float* wp = Wdim + (row << 7) + k8;
        f32x4 v0 = *(const f32x4*)wp;
        f32x4 v1 = *(const f32x4*)(wp + 4);
        u32x4 pk = { pack2bf(v0[0], v0[1]), pack2bf(v0[2], v0[3]),
                     pack2bf(v1[0], v1[1]), pack2bf(v1[2], v1[3]) };
        int byte = (row << 8) + (k8 << 1);
        byte ^= (row & 15) << 4;
        *(u32x4*)(lA + byte) = pk;
    }
    __syncthreads();

    const int lane = t & 63;
    const int wave = t >> 6;
    const int cc = lane & 31;     // node column
    const int h  = lane >> 5;     // k-half within MFMA
    const int tile = blockIdx.x * 4 + wave;
    if (tile >= 3125) return;
    const int node = (tile << 5) + cc;
    const float* xrow = nf + ((size_t)node << 7);

    // stage this lane's half of the row upfront (16 x 16B loads in flight)
    f32x4 rv[16];
#pragma unroll
    for (int kt = 0; kt < 8; ++kt) {
        const int kf = (kt << 4) + (h << 3);
        rv[2*kt]   = *(const f32x4*)(xrow + kf);
        rv[2*kt+1] = *(const f32x4*)(xrow + kf + 4);
    }

    f32x16 acc[4] = {};
#pragma unroll
    for (int kt = 0; kt < 8; ++kt) {                  // K = 128 = 8 * 16
        const int kf = (kt << 4) + (h << 3);
        f32x4 v0 = rv[2*kt], v1 = rv[2*kt+1];
        bf16x8 bf;
        bf[0]=(__bf16)v0[0]; bf[1]=(__bf16)v0[1]; bf[2]=(__bf16)v0[2]; bf[3]=(__bf16)v0[3];
        bf[4]=(__bf16)v1[0]; bf[5]=(__bf16)v1[1]; bf[6]=(__bf16)v1[2]; bf[7]=(__bf16)v1[3];
        const int off = kf << 1;                      // byte offset within LDS row
#pragma unroll
        for (int t4 = 0; t4 < 4; ++t4) {
            const int arow = (t4 << 5) + cc;
            const int ab = ((arow << 8) + off) ^ ((arow & 15) << 4);
            bf16x8 af = __builtin_bit_cast(bf16x8, *(const u32x4*)(lA + ab));
            acc[t4] = __builtin_amdgcn_mfma_f32_32x32x16_bf16(af, bf, acc[t4], 0, 0, 0);
        }
    }
    unsigned short* prow = P + ((size_t)node << 7);
#pragma unroll
    for (int t4 = 0; t4 < 4; ++t4) {
#pragma unroll
        for (int q = 0; q < 4; ++q) {
            const int chb = (t4 << 5) + (q << 3) + (h << 2);
            f32x4 bb = *(const f32x4*)(bdim + chb);
            const float h0 = fmaxf(acc[t4][(q << 2) + 0] + bb[0], 0.f);
            const float h1 = fmaxf(acc[t4][(q << 2) + 1] + bb[1], 0.f);
            const float h2 = fmaxf(acc[t4][(q << 2) + 2] + bb[2], 0.f);
            const float h3 = fmaxf(acc[t4][(q << 2) + 3] + bb[3], 0.f);
            u32x2 st = { pack2bf(h0, h1), pack2bf(h2, h3) };
            *(u32x2*)(prow + chb) = st;
        }
    }
}

// ---------------------------------------------------------------------------
// Kernel 2: per-edge MLP, 32 edges per wave-tile, pipelined nt gathers.
// ---------------------------------------------------------------------------
struct Rows { u32x4 v[16]; };   // [0..7]=src row chunks, [8..15]=dst row chunks

__device__ inline void issue_rows(const unsigned short* __restrict__ P,
                                  int si, int di, int h, Rows& r) {
    const unsigned char* ps = (const unsigned char*)(P + ((size_t)si << 7));
    const unsigned char* pd = (const unsigned char*)(P + ((size_t)di << 7));
#pragma unroll
    for (int kt = 0; kt < 8; ++kt) {
        const int off = (kt << 5) + (h << 4);
        r.v[kt]     = __builtin_nontemporal_load((const u32x4*)(ps + off));
        r.v[8 + kt] = __builtin_nontemporal_load((const u32x4*)(pd + off));
    }
}

__device__ inline void compute_store(const Rows& r, const unsigned char* lA,
                                     const float* __restrict__ b1,
                                     const float* __restrict__ W2, float b2v,
                                     float* __restrict__ out,
                                     int tile, int cc, int h) {
    f32x16 acc[4] = {};
#pragma unroll
    for (int kt = 0; kt < 8; ++kt) {
        const int off = (kt << 5) + (h << 4);
        u32x4 ux = r.v[kt];
        u32x4 uy = r.v[8 + kt];
        bf16x8 bp, bd;
#pragma unroll
        for (int j = 0; j < 4; ++j) {
            const float x0 = bflo(ux[j]), x1 = bfhi(ux[j]);
            const float y0 = bflo(uy[j]), y1 = bfhi(uy[j]);
            bp[2*j]   = (__bf16)(x0 * y0);
            bp[2*j+1] = (__bf16)(x1 * y1);
            bd[2*j]   = (__bf16)(x0 - y0);
            bd[2*j+1] = (__bf16)(x1 - y1);
        }
#pragma unroll
        for (int t4 = 0; t4 < 4; ++t4) {          // product half: W1[:, 0:128]
            const int arow = (t4 << 5) + cc;
            const int ab = ((arow << 9) + off) ^ ((arow & 31) << 4);
            bf16x8 af = __builtin_bit_cast(bf16x8, *(const u32x4*)(lA + ab));
            acc[t4] = __builtin_amdgcn_mfma_f32_32x32x16_bf16(af, bp, acc[t4], 0, 0, 0);
        }
#pragma unroll
        for (int t4 = 0; t4 < 4; ++t4) {          // diff half: W1[:, 128:256]
            const int arow = (t4 << 5) + cc;
            const int ab = ((arow << 9) + 256 + off) ^ ((arow & 31) << 4);
            bf16x8 af = __builtin_bit_cast(bf16x8, *(const u32x4*)(lA + ab));
            acc[t4] = __builtin_amdgcn_mfma_f32_32x32x16_bf16(af, bd, acc[t4], 0, 0, 0);
        }
    }
    float partial = 0.f;
#pragma unroll
    for (int t4 = 0; t4 < 4; ++t4) {
#pragma unroll
        for (int q = 0; q < 4; ++q) {
            const int chb = (t4 << 5) + (q << 3) + (h << 2);
            f32x4 bb = *(const f32x4*)(b1 + chb);
            f32x4 ww = *(const f32x4*)(W2 + chb);
#pragma unroll
            for (int rr = 0; rr < 4; ++rr) {
                const float hv = fmaxf(acc[t4][(q << 2) + rr] + bb[rr], 0.f);
                partial += hv * ww[rr];
            }
        }
    }
    partial += __shfl_xor(partial, 32);           // sum the two k-half groups
    const float z = partial + b2v;
    const float prob = 1.0f / (1.0f + __expf(-z));
    if (h == 0) out[(tile << 5) + cc] = prob;
}

__global__ __launch_bounds__(256, 1) void k_edge(
    const unsigned short* __restrict__ P,
    const int* __restrict__ ei,          // [2][E] int32
    const float* __restrict__ W1, const float* __restrict__ b1,
    const float* __restrict__ W2, const float* __restrict__ b2,
    float* __restrict__ out)
{
    __shared__ unsigned char lA[128 * 512];  // 64 KB: W1 bf16 [128ch][256k]
    const int t = threadIdx.x;
    for (int ci = t; ci < 4096; ci += 256) {          // 4096 chunks of 8
        const int row = ci >> 5;                      // 32 chunks per 256-elem row
        const int k8 = (ci & 31) << 3;
        const float* wp = W1 + (row << 8) + k8;
        f32x4 v0 = *(const f32x4*)wp;
        f32x4 v1 = *(const f32x4*)(wp + 4);
        u32x4 pk = { pack2bf(v0[0], v0[1]), pack2bf(v0[2], v0[3]),
                     pack2bf(v1[0], v1[1]), pack2bf(v1[2], v1[3]) };
        int byte = (row << 9) + (k8 << 1);
        byte ^= (row & 31) << 4;
        *(u32x4*)(lA + byte) = pk;
    }
    __syncthreads();

    const int lane = t & 63;
    const int wave = t >> 6;
    const int cc = lane & 31;     // edge column within tile
    const int h  = lane >> 5;     // k-half
    const float b2v = b2[0];
    const int stride = gridDim.x << 2;

    const int t0 = blockIdx.x * 4 + wave;             // t0 < 2048 <= N_TILES
    int sn, dn;
    Rows A, B;
    {   // tile t0: ei + rows
        const int e0 = t0 << 5;
        const int sc = ei[e0 + cc];
        const int dc = ei[N_EDGES + e0 + cc];
        issue_rows(P, sc, dc, h, A);
    }
    {   // ei for t0+stride
        int tt = t0 + stride; tt = tt < N_TILES ? tt : N_TILES - 1;
        const int e0 = tt << 5;
        sn = ei[e0 + cc];
        dn = ei[N_EDGES + e0 + cc];
    }
    int tl = t0;

#define STEP(CUR, NXT)                                                        \
    {                                                                         \
        issue_rows(P, sn, dn, h, NXT);   /* prefetch rows for tl+stride */    \
        int tt = tl + 2 * stride; tt = tt < N_TILES ? tt : N_TILES - 1;       \
        const int e0n = tt << 5;                                              \
        sn = ei[e0n + cc];                                                    \
        dn = ei[N_EDGES + e0n + cc];                                          \
        compute_store(CUR, lA, b1, W2, b2v, out, tl, cc, h);                  \
        tl += stride;                                                         \
    }

    for (;;) {
        STEP(A, B);
        if (tl >= N_TILES) break;
        STEP(B, A);
        if (tl >= N_TILES) break;
    }
#undef STEP
}

extern "C" void kernel_launch(void* const* d_in, const int* in_sizes, int n_in,
                              void* d_out, int out_size, void* d_ws, size_t ws_size,
                              hipStream_t stream) {
    const float* nf   = (const float*)d_in[0];
    const int*   ei   = (const int*)d_in[1];
    const float* Wdim = (const float*)d_in[2];
    const float* bdim = (const float*)d_in[3];
    const float* W1   = (const float*)d_in[4];
    const float* b1   = (const float*)d_in[5];
    const float* W2   = (const float*)d_in[6];
    const float* b2   = (const float*)d_in[7];
    float* out = (float*)d_out;
    unsigned short* P = (unsigned short*)d_ws;        // 100000*128 bf16 = 25.6 MB

    k_project<<<dim3(782), dim3(256), 0, stream>>>(nf, Wdim, bdim, P);
    k_edge<<<dim3(512), dim3(256), 0, stream>>>(P, ei, W1, b1, W2, b2, out);
}